// Round 8
// baseline (5783.832 us; speedup 1.0000x reference)
//
#include <hip/hip_runtime.h>
#include <math.h>

#define SEQL 64
#define BATCHN 64
#define HID 1024
#define EMBD 1024
#define VOCAB 10000
#define G3 3072
#define NPAD 10240   // 80*128
#define AROWS 4096   // SEQL*BATCHN
#define HSLOT 65536  // BATCHN*HID elements per t-slot

typedef float f4v __attribute__((ext_vector_type(4)));
typedef unsigned short us4 __attribute__((ext_vector_type(4)));
typedef unsigned short us8 __attribute__((ext_vector_type(8)));
typedef __bf16 bf8v __attribute__((ext_vector_type(8)));

__device__ __forceinline__ unsigned short f2bf(float f) {
    unsigned u = __float_as_uint(f);
    u += 0x7fffu + ((u >> 16) & 1u);
    return (unsigned short)(u >> 16);
}
__device__ __forceinline__ float bf2f(unsigned short h) {
    return __uint_as_float(((unsigned)h) << 16);
}
__device__ __forceinline__ void split2(float f, unsigned short &hi, unsigned short &lo) {
    hi = f2bf(f);
    lo = f2bf(f - bf2f(hi));
}
__device__ __forceinline__ f4v mfma16(us8 a, us8 b, f4v c) {
    return __builtin_amdgcn_mfma_f32_16x16x32_bf16(
        __builtin_bit_cast(bf8v, a), __builtin_bit_cast(bf8v, b), c, 0, 0, 0);
}
__device__ __forceinline__ float sigmoidf_(float x) { return 1.f / (1.f + expf(-x)); }

// tiled layout for h within one t-slot: [(b>>4)*32 + (j>>5)][lane=((j>>3)&3)*16+(b&15)][e=j&7]
__device__ __forceinline__ size_t htile_off(int b, int j) {
    return ((size_t)((((b >> 4) * 32 + (j >> 5)) * 64) + ((j >> 3) & 3) * 16 + (b & 15))) * 8 + (j & 7);
}

// ---------------- prep: tile 4 weight matrices into MFMA B-fragment order ----------
// mats: 0=U0, 1=W1, 2=U1, 3=W0
__global__ __launch_bounds__(256)
void tile_weights_kernel(const float* __restrict__ U0, const float* __restrict__ W1,
                         const float* __restrict__ U1, const float* __restrict__ W0,
                         unsigned short* __restrict__ hi, unsigned short* __restrict__ lo)
{
    __shared__ float tile[32][65];
    const int mat = blockIdx.z;
    const float* src = (mat == 0) ? U0 : (mat == 1) ? W1 : (mat == 2) ? U1 : W0;
    const int n0 = blockIdx.x * 64, k0 = blockIdx.y * 32;
    const int t = threadIdx.x, tx = t & 63, ty = t >> 6;
#pragma unroll
    for (int s = 0; s < 8; s++)
        tile[ty * 8 + s][tx] = src[(size_t)(k0 + ty * 8 + s) * G3 + n0 + tx];
    __syncthreads();
    const int c = t >> 6, lane = t & 63, fr = lane & 15, kg = lane >> 4;
    const int cc = (n0 >> 4) + c;
    const size_t off = (((size_t)(mat * 192 + cc) * 32 + (k0 >> 5)) * 64 + lane) * 8;
    us8 h8, l8;
#pragma unroll
    for (int e = 0; e < 8; e++) {
        unsigned short a, b;
        split2(tile[kg * 8 + e][c * 16 + fr], a, b);
        h8[e] = a; l8[e] = b;
    }
    *(us8*)(hi + off) = h8;
    *(us8*)(lo + off) = l8;
}

// ---------------- prep (late): pad fcW to NPAD rows + hi/lo split ----------
__global__ void fc_pad_split_kernel(const float* __restrict__ fcW,
                                    unsigned short* __restrict__ hi, unsigned short* __restrict__ lo)
{
    size_t i = ((size_t)blockIdx.x * 256 + threadIdx.x) * 4;
    size_t row = i >> 10;
    f4v v = {0.f, 0.f, 0.f, 0.f};
    if (row < VOCAB) v = *(const f4v*)(fcW + i);
    us4 h, l;
#pragma unroll
    for (int j = 0; j < 4; j++) { unsigned short a, b; split2(v[j], a, b); h[j] = a; l[j] = b; }
    *(us4*)(hi + i) = h;
    *(us4*)(lo + i) = l;
}

__global__ void fcb_pad_kernel(const float* __restrict__ fcb, float* __restrict__ fcb_pad)
{
    int idx = blockIdx.x * 256 + threadIdx.x;
    if (idx < NPAD) fcb_pad[idx] = (idx < VOCAB) ? fcb[idx] : 0.f;
}

// ---------------- prep: initial hidden -> tiled hi/lo ; zero step counters ----------
__global__ void small_prep_kernel(const float* __restrict__ hidden,
                                  unsigned short* __restrict__ h0th, unsigned short* __restrict__ h0tl,
                                  unsigned short* __restrict__ h1th, unsigned short* __restrict__ h1tl,
                                  int* __restrict__ cnt)
{
    int idx = blockIdx.x * 256 + threadIdx.x;
    if (idx < 65 * 64) cnt[idx] = 0;
    if (idx < BATCHN * HID) {
        int b = idx >> 10, j = idx & 1023;
        size_t o = htile_off(b, j);
        unsigned short a1, b1;
        split2(hidden[idx], a1, b1);                 h0th[o] = a1; h0tl[o] = b1;
        split2(hidden[BATCHN * HID + idx], a1, b1);  h1th[o] = a1; h1tl[o] = b1;
    }
}

// ---------------- GX0 = gather(emb,tok) @ W0 ----------
__global__ __launch_bounds__(256)
void gx0_gemm_kernel(const int* __restrict__ tok, const float* __restrict__ emb,
                     const unsigned short* __restrict__ Wthi, const unsigned short* __restrict__ Wtlo,
                     float* __restrict__ C)
{
    __shared__ unsigned short Ah[128][40], Al[128][40];
    const int bswz = blockIdx.x;
    const int xcd = bswz & 7, s = bswz >> 3;
    const int col0 = (xcd + 8 * (s >> 5)) * 128;   // 24 col-tiles
    const int row0 = (s & 31) * 128;               // 32 row-tiles
    const int tid = threadIdx.x;
    const int lane = tid & 63, wave = tid >> 6;
    const int wm = wave >> 1, wn = wave & 1;
    const int srow = tid >> 1;
    const int shalf = (tid & 1) * 16;

    const float* asrc = emb + (size_t)tok[row0 + srow] * EMBD + shalf;
    const int fr = lane & 15, fk = (lane >> 4) * 8;
    const int cc0 = (col0 >> 4) + wn * 4;

    f4v a[4];
#pragma unroll
    for (int q = 0; q < 4; q++) a[q] = *(const f4v*)(asrc + q * 4);

    f4v acc[4][4] = {};
    for (int k0 = 0; k0 < EMBD; k0 += 32) {
        __syncthreads();
        us8 ahv[2], alv[2];
#pragma unroll
        for (int q = 0; q < 4; q++)
#pragma unroll
            for (int j = 0; j < 4; j++) {
                unsigned short h, l;
                split2(a[q][j], h, l);
                ahv[q >> 1][(q & 1) * 4 + j] = h;
                alv[q >> 1][(q & 1) * 4 + j] = l;
            }
        *(us8*)(&Ah[srow][shalf]) = ahv[0];     *(us8*)(&Ah[srow][shalf + 8]) = ahv[1];
        *(us8*)(&Al[srow][shalf]) = alv[0];     *(us8*)(&Al[srow][shalf + 8]) = alv[1];
        __syncthreads();
        if (k0 + 32 < EMBD) {
#pragma unroll
            for (int q = 0; q < 4; q++) a[q] = *(const f4v*)(asrc + k0 + 32 + q * 4);
        }
        const int ks = k0 >> 5;
        us8 bfh[4], bfl[4];
#pragma unroll
        for (int n = 0; n < 4; n++) {
            const size_t bo = (((size_t)(3 * 192 + cc0 + n) * 32 + ks) * 64 + lane) * 8;
            bfh[n] = *(const us8*)(Wthi + bo);
            bfl[n] = *(const us8*)(Wtlo + bo);
        }
        us8 afh[4], afl[4];
#pragma unroll
        for (int m = 0; m < 4; m++) {
            afh[m] = *(const us8*)(&Ah[wm * 64 + m * 16 + fr][fk]);
            afl[m] = *(const us8*)(&Al[wm * 64 + m * 16 + fr][fk]);
        }
#pragma unroll
        for (int n = 0; n < 4; n++)
#pragma unroll
            for (int m = 0; m < 4; m++) {
                acc[m][n] = mfma16(afh[m], bfh[n], acc[m][n]);
                acc[m][n] = mfma16(afh[m], bfl[n], acc[m][n]);
                acc[m][n] = mfma16(afl[m], bfh[n], acc[m][n]);
            }
    }
    const int fq = lane >> 4;
#pragma unroll
    for (int m = 0; m < 4; m++)
#pragma unroll
        for (int n = 0; n < 4; n++)
#pragma unroll
            for (int i = 0; i < 4; i++) {
                int r = row0 + wm * 64 + m * 16 + fq * 4 + i;
                int c = col0 + wn * 64 + n * 16 + fr;
                C[(size_t)r * G3 + c] = acc[m][n][i];
            }
}

// ---------------- logits = H1 @ fcW^T + fcb ----------
__global__ __launch_bounds__(256)
void logits_gemm_kernel(const unsigned short* __restrict__ h1t_hi, const unsigned short* __restrict__ h1t_lo,
                        const unsigned short* __restrict__ Bhi, const unsigned short* __restrict__ Blo,
                        const float* __restrict__ bias, float* __restrict__ C)
{
    __shared__ unsigned short Bh[128][40], Bl[128][40];
    const int bswz = blockIdx.x;
    const int xcd = bswz & 7, s = bswz >> 3;
    const int col0 = (xcd + 8 * (s >> 5)) * 128;   // 80 col-tiles
    const int row0 = (s & 31) * 128;               // 32 row-tiles
    const int t0 = row0 >> 6;
    const int tid = threadIdx.x;
    const int lane = tid & 63, wave = tid >> 6;
    const int wm = wave >> 1, wn = wave & 1;
    const int srow = tid >> 1;
    const int shalf = (tid & 1) * 16;

    const unsigned short* bh_src = Bhi + (size_t)(col0 + srow) * HID + shalf;
    const unsigned short* bl_src = Blo + (size_t)(col0 + srow) * HID + shalf;

    f4v acc[4][4] = {};
    us8 bh2[2], bl2[2];
    bh2[0] = *(const us8*)(bh_src);  bh2[1] = *(const us8*)(bh_src + 8);
    bl2[0] = *(const us8*)(bl_src);  bl2[1] = *(const us8*)(bl_src + 8);

    const int fr = lane & 15, fk = (lane >> 4) * 8;
    const size_t abase = ((size_t)(t0 + wm) * 128) * 512 + (size_t)lane * 8;

    for (int k0 = 0; k0 < HID; k0 += 32) {
        __syncthreads();
        *(us8*)(&Bh[srow][shalf]) = bh2[0];  *(us8*)(&Bh[srow][shalf + 8]) = bh2[1];
        *(us8*)(&Bl[srow][shalf]) = bl2[0];  *(us8*)(&Bl[srow][shalf + 8]) = bl2[1];
        __syncthreads();
        if (k0 + 32 < HID) {
            bh2[0] = *(const us8*)(bh_src + k0 + 32);  bh2[1] = *(const us8*)(bh_src + k0 + 40);
            bl2[0] = *(const us8*)(bl_src + k0 + 32);  bl2[1] = *(const us8*)(bl_src + k0 + 40);
        }
        const int ks = k0 >> 5;
        us8 afh[4], afl[4];
#pragma unroll
        for (int m = 0; m < 4; m++) {
            const size_t ao = abase + (size_t)(m * 32 + ks) * 512;
            afh[m] = *(const us8*)(h1t_hi + ao);
            afl[m] = *(const us8*)(h1t_lo + ao);
        }
#pragma unroll
        for (int n = 0; n < 4; n++) {
            us8 bfh = *(const us8*)(&Bh[wn * 64 + n * 16 + fr][fk]);
            us8 bfl = *(const us8*)(&Bl[wn * 64 + n * 16 + fr][fk]);
#pragma unroll
            for (int m = 0; m < 4; m++) {
                acc[m][n] = mfma16(afh[m], bfh, acc[m][n]);
                acc[m][n] = mfma16(afh[m], bfl, acc[m][n]);
                acc[m][n] = mfma16(afl[m], bfh, acc[m][n]);
            }
        }
    }
    const int fq = lane >> 4;
#pragma unroll
    for (int m = 0; m < 4; m++)
#pragma unroll
        for (int n = 0; n < 4; n++)
#pragma unroll
            for (int i = 0; i < 4; i++) {
                int r = row0 + wm * 64 + m * 16 + fq * 4 + i;
                int c = col0 + wn * 64 + n * 16 + fr;
                float v = acc[m][n][i] + bias[c];
                if (c < VOCAB) C[(size_t)r * VOCAB + c] = v;
            }
}

// ---------------- fused step: R7 spill-free gemm + R6 validated threadfence tail ----------
// grid 256 = 64 jc x 4 kq, 512 thr = 8 waves, 1 block/CU (256 VGPR budget, no spill).
// Wave w owns ks=kq*8+w, m-loop x4: every weight/A byte read once per block.
// Two-phase A-register reuse (h0 frags for t2<6, h1 frags for t2>=6).
// 8->1 LDS tree reduce; wave 0 writes kq-partial to P; threadfence + atomicAdd counter;
// the 4th-arriving block per jc re-fences and does the 4-kq sum + GRU pointwise (pattern
// validated end-to-end in R6: passed both call-1 and post-timing checks).
template <int T0, int T1>
__global__ __launch_bounds__(512, 1)
void step_fused_kernel(const unsigned short* __restrict__ h0hi, const unsigned short* __restrict__ h0lo,
                       const unsigned short* __restrict__ h1hi, const unsigned short* __restrict__ h1lo,
                       const unsigned short* __restrict__ Wthi, const unsigned short* __restrict__ Wtlo,
                       const float* __restrict__ gx0next,
                       const float* __restrict__ bw0, const float* __restrict__ bu0,
                       const float* __restrict__ bw1, const float* __restrict__ bu1,
                       float* __restrict__ P, int* __restrict__ cntRow,
                       unsigned short* __restrict__ h0o_hi, unsigned short* __restrict__ h0o_lo,
                       unsigned short* __restrict__ h1o_hi, unsigned short* __restrict__ h1o_lo)
{
    const int tid = threadIdx.x, lane = tid & 63, wave = tid >> 6;
    const int jc = blockIdx.x >> 2, kq = blockIdx.x & 3;
    const int ks = kq * 8 + wave;
    const size_t abase = ((size_t)ks * 64 + lane) * 8;

    f4v acc[9][4] = {};
    us8 ah[4], al[4];

    // phase A: t2 in [T0, min(6,T1)) uses h0 fragments
    if (T0 < 6) {
#pragma unroll
        for (int m = 0; m < 4; m++) {
            ah[m] = *(const us8*)(h0hi + abase + (size_t)m * 16384);
            al[m] = *(const us8*)(h0lo + abase + (size_t)m * 16384);
        }
#pragma unroll
        for (int t2 = T0; t2 < ((T1 < 6) ? T1 : 6); ++t2) {
            const int mat = t2 / 3, g = t2 % 3;
            const size_t base = (((size_t)(mat * 192 + g * 64 + jc) * 32 + ks) * 64 + lane) * 8;
            us8 bh = *(const us8*)(Wthi + base);
            us8 bl = *(const us8*)(Wtlo + base);
#pragma unroll
            for (int m = 0; m < 4; ++m) {
                acc[t2][m] = mfma16(ah[m], bh, acc[t2][m]);
                acc[t2][m] = mfma16(ah[m], bl, acc[t2][m]);
                acc[t2][m] = mfma16(al[m], bh, acc[t2][m]);
            }
        }
    }
    // phase B: t2 in [6, T1) uses h1 fragments (reuse the same registers)
    if (T1 > 6) {
#pragma unroll
        for (int m = 0; m < 4; m++) {
            ah[m] = *(const us8*)(h1hi + abase + (size_t)m * 16384);
            al[m] = *(const us8*)(h1lo + abase + (size_t)m * 16384);
        }
#pragma unroll
        for (int t2 = 6; t2 < T1; ++t2) {
            const int g = t2 % 3;
            const size_t base = (((size_t)(2 * 192 + g * 64 + jc) * 32 + ks) * 64 + lane) * 8;
            us8 bh = *(const us8*)(Wthi + base);
            us8 bl = *(const us8*)(Wtlo + base);
#pragma unroll
            for (int m = 0; m < 4; ++m) {
                acc[t2][m] = mfma16(ah[m], bh, acc[t2][m]);
                acc[t2][m] = mfma16(ah[m], bl, acc[t2][m]);
                acc[t2][m] = mfma16(al[m], bh, acc[t2][m]);
            }
        }
    }

    // 8 -> 1 tree reduce over waves, chunked 3 t2 at a time (48 KB LDS)
    __shared__ f4v red[4][3][4][64];
    const int c0lo = T0 / 3, c0hi = (T1 + 2) / 3;
#pragma unroll
    for (int stride = 4; stride >= 1; stride >>= 1) {
#pragma unroll
        for (int c = c0lo; c < c0hi; ++c) {
            if (wave >= stride && wave < 2 * stride) {
#pragma unroll
                for (int u = 0; u < 3; ++u) {
                    const int t2 = c * 3 + u;
                    if (t2 >= T0 && t2 < T1) {
#pragma unroll
                        for (int m = 0; m < 4; ++m)
                            red[wave - stride][u][m][lane] = acc[t2][m];
                    }
                }
            }
            __syncthreads();
            if (wave < stride) {
#pragma unroll
                for (int u = 0; u < 3; ++u) {
                    const int t2 = c * 3 + u;
                    if (t2 >= T0 && t2 < T1) {
#pragma unroll
                        for (int m = 0; m < 4; ++m)
                            acc[t2][m] += red[wave][u][m][lane];
                    }
                }
            }
            __syncthreads();
        }
    }

    if (wave == 0) {
        const int rrow = (lane >> 4) * 4, rcol = lane & 15;
#pragma unroll
        for (int t2 = T0; t2 < T1; ++t2)
#pragma unroll
            for (int m = 0; m < 4; ++m)
#pragma unroll
                for (int i = 0; i < 4; ++i)
                    P[(((size_t)kq * 9 + t2) * 64 + (m * 16 + rrow + i)) * 1024 + jc * 16 + rcol]
                        = acc[t2][m][i];
    }
    __threadfence();          // release: make P visible at device scope
    __syncthreads();
    __shared__ int lastFlag;
    if (tid == 0) lastFlag = (atomicAdd(cntRow + jc, 1) == 3);
    __syncthreads();
    if (!lastFlag) return;
    __threadfence();          // acquire: invalidate stale lines before reading P

    // tail: 4-kq sum + GRU pointwise for this jc (1024 elements, 2 per thread)
#pragma unroll
    for (int k = 0; k < 2; ++k) {
        const int idx = k * 512 + tid;
        const int b = idx >> 4, j = jc * 16 + (idx & 15);
        float G[9] = {};
#pragma unroll
        for (int t2 = T0; t2 < T1; ++t2) {
            const float* p = P + ((size_t)t2 * 64 + b) * 1024 + j;
            G[t2] = (p[0] + p[(size_t)9 * 64 * 1024])
                  + (p[(size_t)18 * 64 * 1024] + p[(size_t)27 * 64 * 1024]);
        }
        const size_t po = htile_off(b, j);
        if (T0 == 0) {
            float sr  = gx0next[(size_t)b * G3 + j]            + bw0[j]           + G[0] + bu0[j];
            float sz  = gx0next[(size_t)b * G3 + HID + j]      + bw0[HID + j]     + G[1] + bu0[HID + j];
            float gxn = gx0next[(size_t)b * G3 + 2 * HID + j]  + bw0[2 * HID + j];
            float ghn = G[2] + bu0[2 * HID + j];
            float r = sigmoidf_(sr);
            float z = sigmoidf_(sz);
            float ht = tanhf(gxn + r * ghn);
            float hp = bf2f(h0hi[po]) + bf2f(h0lo[po]);
            float hn = (1.f - z) * hp + z * ht;
            unsigned short hh, hl2; split2(hn, hh, hl2);
            h0o_hi[po] = hh; h0o_lo[po] = hl2;
        }
        if (T1 > 3) {
            float sr  = G[3] + bw1[j]           + G[6] + bu1[j];
            float sz  = G[4] + bw1[HID + j]     + G[7] + bu1[HID + j];
            float gxn = G[5] + bw1[2 * HID + j];
            float ghn = G[8] + bu1[2 * HID + j];
            float r = sigmoidf_(sr);
            float z = sigmoidf_(sz);
            float ht = tanhf(gxn + r * ghn);
            float hp = bf2f(h1hi[po]) + bf2f(h1lo[po]);
            float hn = (1.f - z) * hp + z * ht;
            unsigned short hh, hl2; split2(hn, hh, hl2);
            h1o_hi[po] = hh; h1o_lo[po] = hl2;
        }
    }
}

// ---------------- final hidden output ----------
__global__ void hidden_out_kernel(const unsigned short* __restrict__ h0hi, const unsigned short* __restrict__ h0lo,
                                  const unsigned short* __restrict__ h1hi, const unsigned short* __restrict__ h1lo,
                                  float* __restrict__ out)
{
    int i = blockIdx.x * 256 + threadIdx.x;
    if (i < BATCHN * HID) {
        int b = i >> 10, j = i & 1023;
        size_t o = htile_off(b, j);
        out[i] = bf2f(h0hi[o]) + bf2f(h0lo[o]);
        out[BATCHN * HID + i] = bf2f(h1hi[o]) + bf2f(h1lo[o]);
    }
}

extern "C" void kernel_launch(void* const* d_in, const int* in_sizes, int n_in,
                              void* d_out, int out_size, void* d_ws, size_t ws_size,
                              hipStream_t stream)
{
    (void)in_sizes; (void)n_in; (void)out_size;
    const int*   tok    = (const int*)  d_in[0];
    const float* hidden = (const float*)d_in[1];
    const float* emb    = (const float*)d_in[2];
    const float* W0     = (const float*)d_in[3];
    const float* U0     = (const float*)d_in[4];
    const float* bw0    = (const float*)d_in[5];
    const float* bu0    = (const float*)d_in[6];
    const float* W1     = (const float*)d_in[7];
    const float* U1     = (const float*)d_in[8];
    const float* bw1    = (const float*)d_in[9];
    const float* bu1    = (const float*)d_in[10];
    const float* fcW    = (const float*)d_in[11];
    const float* fcb    = (const float*)d_in[12];
    float* out = (float*)d_out;

    char* wsp = (char*)d_ws;
    size_t used = 0;
    auto alloc = [&](size_t bytes) -> char* {
        char* p = wsp + used;
        used += (bytes + 255) & ~(size_t)255;
        return p;
    };
    unsigned short* Wt_hi = (unsigned short*)alloc((size_t)4 * G3 * HID * 2);   // 25.2 MB
    unsigned short* Wt_lo = (unsigned short*)alloc((size_t)4 * G3 * HID * 2);   // 25.2 MB
    float*          GX0   = (float*)alloc((size_t)AROWS * G3 * 4);              // 50.3 MB
    unsigned short* H0Thi = (unsigned short*)alloc((size_t)SEQL * HSLOT * 2);   // 8.4 MB
    unsigned short* H0Tlo = (unsigned short*)alloc((size_t)SEQL * HSLOT * 2);
    unsigned short* H1Thi = (unsigned short*)alloc((size_t)SEQL * HSLOT * 2);
    unsigned short* H1Tlo = (unsigned short*)alloc((size_t)SEQL * HSLOT * 2);
    float*          P0    = (float*)alloc((size_t)4 * 9 * BATCHN * HID * 4);    // 9.4 MB
    float*          P1    = (float*)alloc((size_t)4 * 9 * BATCHN * HID * 4);    // 9.4 MB
    int*            cnt   = (int*)alloc((size_t)65 * 64 * 4);                   // 16.6 KB
    unsigned short* h0ith = (unsigned short*)alloc((size_t)HSLOT * 2);
    unsigned short* h0itl = (unsigned short*)alloc((size_t)HSLOT * 2);
    unsigned short* h1ith = (unsigned short*)alloc((size_t)HSLOT * 2);
    unsigned short* h1itl = (unsigned short*)alloc((size_t)HSLOT * 2);
    if (used > ws_size) return;  // ~154 MB needed

    unsigned short* fcWhi = Wt_hi;   // aliases dead Wt space (used only after last step)
    unsigned short* fcWlo = Wt_lo;
    float*          fcbp  = (float*)((char*)Wt_hi + (size_t)NPAD * HID * 2);

    tile_weights_kernel<<<dim3(48, 32, 4), 256, 0, stream>>>(U0, W1, U1, W0, Wt_hi, Wt_lo);
    small_prep_kernel<<<256, 256, 0, stream>>>(hidden, h0ith, h0itl, h1ith, h1itl, cnt);
    gx0_gemm_kernel<<<768, 256, 0, stream>>>(tok, emb, Wt_hi, Wt_lo, GX0);

    // prologue: h0_0 = GRU0(gx0[0], h_init0)
    step_fused_kernel<0, 3><<<256, 512, 0, stream>>>(
        h0ith, h0itl, h1ith, h1itl, Wt_hi, Wt_lo,
        GX0, bw0, bu0, bw1, bu1, P0, cnt,
        H0Thi, H0Tlo,                                       // h0_0 -> slot 0
        H1Thi + (size_t)63 * HSLOT, H1Tlo + (size_t)63 * HSLOT);  // unused (compiled out)

    for (int t = 0; t < 63; t++) {
        const unsigned short* h0h = H0Thi + (size_t)t * HSLOT;
        const unsigned short* h0l = H0Tlo + (size_t)t * HSLOT;
        const unsigned short* a1h = (t == 0) ? h1ith : H1Thi + (size_t)(t - 1) * HSLOT;
        const unsigned short* a1l = (t == 0) ? h1itl : H1Tlo + (size_t)(t - 1) * HSLOT;
        float* Pb = ((t & 1) == 0) ? P1 : P0;
        step_fused_kernel<0, 9><<<256, 512, 0, stream>>>(
            h0h, h0l, a1h, a1l, Wt_hi, Wt_lo,
            GX0 + (size_t)(t + 1) * BATCHN * G3, bw0, bu0, bw1, bu1,
            Pb, cnt + (size_t)(t + 1) * 64,
            H0Thi + (size_t)(t + 1) * HSLOT, H0Tlo + (size_t)(t + 1) * HSLOT,  // h0_{t+1}
            H1Thi + (size_t)t * HSLOT, H1Tlo + (size_t)t * HSLOT);             // h1_t
    }
    // t = 63: layer-1 only
    step_fused_kernel<3, 9><<<256, 512, 0, stream>>>(
        H0Thi + (size_t)63 * HSLOT, H0Tlo + (size_t)63 * HSLOT,
        H1Thi + (size_t)62 * HSLOT, H1Tlo + (size_t)62 * HSLOT,
        Wt_hi, Wt_lo,
        GX0, bw0, bu0, bw1, bu1, P0, cnt + (size_t)64 * 64,
        h0ith, h0itl,                                              // unused (compiled out)
        H1Thi + (size_t)63 * HSLOT, H1Tlo + (size_t)63 * HSLOT);   // h1_63

    hidden_out_kernel<<<256, 256, 0, stream>>>(
        H0Thi + (size_t)63 * HSLOT, H0Tlo + (size_t)63 * HSLOT,
        H1Thi + (size_t)63 * HSLOT, H1Tlo + (size_t)63 * HSLOT,
        out + (size_t)AROWS * VOCAB);

    fc_pad_split_kernel<<<NPAD, 256, 0, stream>>>(fcW, fcWhi, fcWlo);
    fcb_pad_kernel<<<(NPAD + 255) / 256, 256, 0, stream>>>(fcb, fcbp);
    logits_gemm_kernel<<<2560, 256, 0, stream>>>(
        H1Thi, H1Tlo, fcWhi, fcWlo, fcbp, out);
}

// Round 9
// 2343.548 us; speedup vs baseline: 2.4680x; 2.4680x over previous
//
#include <hip/hip_runtime.h>
#include <math.h>

#define SEQL 64
#define BATCHN 64
#define HID 1024
#define EMBD 1024
#define VOCAB 10000
#define G3 3072
#define NPAD 10240   // 80*128
#define AROWS 4096   // SEQL*BATCHN
#define HSLOT 65536  // BATCHN*HID elements per t-slot

typedef float f4v __attribute__((ext_vector_type(4)));
typedef unsigned short us4 __attribute__((ext_vector_type(4)));
typedef unsigned short us8 __attribute__((ext_vector_type(8)));
typedef __bf16 bf8v __attribute__((ext_vector_type(8)));

__device__ __forceinline__ unsigned short f2bf(float f) {
    unsigned u = __float_as_uint(f);
    u += 0x7fffu + ((u >> 16) & 1u);
    return (unsigned short)(u >> 16);
}
__device__ __forceinline__ float bf2f(unsigned short h) {
    return __uint_as_float(((unsigned)h) << 16);
}
__device__ __forceinline__ void split2(float f, unsigned short &hi, unsigned short &lo) {
    hi = f2bf(f);
    lo = f2bf(f - bf2f(hi));
}
__device__ __forceinline__ f4v mfma16(us8 a, us8 b, f4v c) {
    return __builtin_amdgcn_mfma_f32_16x16x32_bf16(
        __builtin_bit_cast(bf8v, a), __builtin_bit_cast(bf8v, b), c, 0, 0, 0);
}
__device__ __forceinline__ float sigmoidf_(float x) { return 1.f / (1.f + expf(-x)); }

// tiled layout for h within one t-slot: [(b>>4)*32 + (j>>5)][lane=((j>>3)&3)*16+(b&15)][e=j&7]
__device__ __forceinline__ size_t htile_off(int b, int j) {
    return ((size_t)((((b >> 4) * 32 + (j >> 5)) * 64) + ((j >> 3) & 3) * 16 + (b & 15))) * 8 + (j & 7);
}

// ---------------- prep: tile 4 weight matrices into MFMA B-fragment order ----------
// mats: 0=U0, 1=W1, 2=U1, 3=W0
__global__ __launch_bounds__(256)
void tile_weights_kernel(const float* __restrict__ U0, const float* __restrict__ W1,
                         const float* __restrict__ U1, const float* __restrict__ W0,
                         unsigned short* __restrict__ hi, unsigned short* __restrict__ lo)
{
    __shared__ float tile[32][65];
    const int mat = blockIdx.z;
    const float* src = (mat == 0) ? U0 : (mat == 1) ? W1 : (mat == 2) ? U1 : W0;
    const int n0 = blockIdx.x * 64, k0 = blockIdx.y * 32;
    const int t = threadIdx.x, tx = t & 63, ty = t >> 6;
#pragma unroll
    for (int s = 0; s < 8; s++)
        tile[ty * 8 + s][tx] = src[(size_t)(k0 + ty * 8 + s) * G3 + n0 + tx];
    __syncthreads();
    const int c = t >> 6, lane = t & 63, fr = lane & 15, kg = lane >> 4;
    const int cc = (n0 >> 4) + c;
    const size_t off = (((size_t)(mat * 192 + cc) * 32 + (k0 >> 5)) * 64 + lane) * 8;
    us8 h8, l8;
#pragma unroll
    for (int e = 0; e < 8; e++) {
        unsigned short a, b;
        split2(tile[kg * 8 + e][c * 16 + fr], a, b);
        h8[e] = a; l8[e] = b;
    }
    *(us8*)(hi + off) = h8;
    *(us8*)(lo + off) = l8;
}

// ---------------- prep (late): pad fcW to NPAD rows + hi/lo split ----------
__global__ void fc_pad_split_kernel(const float* __restrict__ fcW,
                                    unsigned short* __restrict__ hi, unsigned short* __restrict__ lo)
{
    size_t i = ((size_t)blockIdx.x * 256 + threadIdx.x) * 4;
    size_t row = i >> 10;
    f4v v = {0.f, 0.f, 0.f, 0.f};
    if (row < VOCAB) v = *(const f4v*)(fcW + i);
    us4 h, l;
#pragma unroll
    for (int j = 0; j < 4; j++) { unsigned short a, b; split2(v[j], a, b); h[j] = a; l[j] = b; }
    *(us4*)(hi + i) = h;
    *(us4*)(lo + i) = l;
}

__global__ void fcb_pad_kernel(const float* __restrict__ fcb, float* __restrict__ fcb_pad)
{
    int idx = blockIdx.x * 256 + threadIdx.x;
    if (idx < NPAD) fcb_pad[idx] = (idx < VOCAB) ? fcb[idx] : 0.f;
}

// ---------------- prep: initial hidden -> tiled hi/lo ----------
__global__ void small_prep_kernel(const float* __restrict__ hidden,
                                  unsigned short* __restrict__ h0th, unsigned short* __restrict__ h0tl,
                                  unsigned short* __restrict__ h1th, unsigned short* __restrict__ h1tl)
{
    int idx = blockIdx.x * 256 + threadIdx.x;
    if (idx < BATCHN * HID) {
        int b = idx >> 10, j = idx & 1023;
        size_t o = htile_off(b, j);
        unsigned short a1, b1;
        split2(hidden[idx], a1, b1);                 h0th[o] = a1; h0tl[o] = b1;
        split2(hidden[BATCHN * HID + idx], a1, b1);  h1th[o] = a1; h1tl[o] = b1;
    }
}

// ---------------- GX0 = gather(emb,tok) @ W0 ----------
__global__ __launch_bounds__(256)
void gx0_gemm_kernel(const int* __restrict__ tok, const float* __restrict__ emb,
                     const unsigned short* __restrict__ Wthi, const unsigned short* __restrict__ Wtlo,
                     float* __restrict__ C)
{
    __shared__ unsigned short Ah[128][40], Al[128][40];
    const int bswz = blockIdx.x;
    const int xcd = bswz & 7, s = bswz >> 3;
    const int col0 = (xcd + 8 * (s >> 5)) * 128;   // 24 col-tiles
    const int row0 = (s & 31) * 128;               // 32 row-tiles
    const int tid = threadIdx.x;
    const int lane = tid & 63, wave = tid >> 6;
    const int wm = wave >> 1, wn = wave & 1;
    const int srow = tid >> 1;
    const int shalf = (tid & 1) * 16;

    const float* asrc = emb + (size_t)tok[row0 + srow] * EMBD + shalf;
    const int fr = lane & 15, fk = (lane >> 4) * 8;
    const int cc0 = (col0 >> 4) + wn * 4;

    f4v a[4];
#pragma unroll
    for (int q = 0; q < 4; q++) a[q] = *(const f4v*)(asrc + q * 4);

    f4v acc[4][4] = {};
    for (int k0 = 0; k0 < EMBD; k0 += 32) {
        __syncthreads();
        us8 ahv[2], alv[2];
#pragma unroll
        for (int q = 0; q < 4; q++)
#pragma unroll
            for (int j = 0; j < 4; j++) {
                unsigned short h, l;
                split2(a[q][j], h, l);
                ahv[q >> 1][(q & 1) * 4 + j] = h;
                alv[q >> 1][(q & 1) * 4 + j] = l;
            }
        *(us8*)(&Ah[srow][shalf]) = ahv[0];     *(us8*)(&Ah[srow][shalf + 8]) = ahv[1];
        *(us8*)(&Al[srow][shalf]) = alv[0];     *(us8*)(&Al[srow][shalf + 8]) = alv[1];
        __syncthreads();
        if (k0 + 32 < EMBD) {
#pragma unroll
            for (int q = 0; q < 4; q++) a[q] = *(const f4v*)(asrc + k0 + 32 + q * 4);
        }
        const int ks = k0 >> 5;
        us8 bfh[4], bfl[4];
#pragma unroll
        for (int n = 0; n < 4; n++) {
            const size_t bo = (((size_t)(3 * 192 + cc0 + n) * 32 + ks) * 64 + lane) * 8;
            bfh[n] = *(const us8*)(Wthi + bo);
            bfl[n] = *(const us8*)(Wtlo + bo);
        }
        us8 afh[4], afl[4];
#pragma unroll
        for (int m = 0; m < 4; m++) {
            afh[m] = *(const us8*)(&Ah[wm * 64 + m * 16 + fr][fk]);
            afl[m] = *(const us8*)(&Al[wm * 64 + m * 16 + fr][fk]);
        }
#pragma unroll
        for (int n = 0; n < 4; n++)
#pragma unroll
            for (int m = 0; m < 4; m++) {
                acc[m][n] = mfma16(afh[m], bfh[n], acc[m][n]);
                acc[m][n] = mfma16(afh[m], bfl[n], acc[m][n]);
                acc[m][n] = mfma16(afl[m], bfh[n], acc[m][n]);
            }
    }
    const int fq = lane >> 4;
#pragma unroll
    for (int m = 0; m < 4; m++)
#pragma unroll
        for (int n = 0; n < 4; n++)
#pragma unroll
            for (int i = 0; i < 4; i++) {
                int r = row0 + wm * 64 + m * 16 + fq * 4 + i;
                int c = col0 + wn * 64 + n * 16 + fr;
                C[(size_t)r * G3 + c] = acc[m][n][i];
            }
}

// ---------------- logits = H1 @ fcW^T + fcb ----------
__global__ __launch_bounds__(256)
void logits_gemm_kernel(const unsigned short* __restrict__ h1t_hi, const unsigned short* __restrict__ h1t_lo,
                        const unsigned short* __restrict__ Bhi, const unsigned short* __restrict__ Blo,
                        const float* __restrict__ bias, float* __restrict__ C)
{
    __shared__ unsigned short Bh[128][40], Bl[128][40];
    const int bswz = blockIdx.x;
    const int xcd = bswz & 7, s = bswz >> 3;
    const int col0 = (xcd + 8 * (s >> 5)) * 128;   // 80 col-tiles
    const int row0 = (s & 31) * 128;               // 32 row-tiles
    const int t0 = row0 >> 6;
    const int tid = threadIdx.x;
    const int lane = tid & 63, wave = tid >> 6;
    const int wm = wave >> 1, wn = wave & 1;
    const int srow = tid >> 1;
    const int shalf = (tid & 1) * 16;

    const unsigned short* bh_src = Bhi + (size_t)(col0 + srow) * HID + shalf;
    const unsigned short* bl_src = Blo + (size_t)(col0 + srow) * HID + shalf;

    f4v acc[4][4] = {};
    us8 bh2[2], bl2[2];
    bh2[0] = *(const us8*)(bh_src);  bh2[1] = *(const us8*)(bh_src + 8);
    bl2[0] = *(const us8*)(bl_src);  bl2[1] = *(const us8*)(bl_src + 8);

    const int fr = lane & 15, fk = (lane >> 4) * 8;
    const size_t abase = ((size_t)(t0 + wm) * 128) * 512 + (size_t)lane * 8;

    for (int k0 = 0; k0 < HID; k0 += 32) {
        __syncthreads();
        *(us8*)(&Bh[srow][shalf]) = bh2[0];  *(us8*)(&Bh[srow][shalf + 8]) = bh2[1];
        *(us8*)(&Bl[srow][shalf]) = bl2[0];  *(us8*)(&Bl[srow][shalf + 8]) = bl2[1];
        __syncthreads();
        if (k0 + 32 < HID) {
            bh2[0] = *(const us8*)(bh_src + k0 + 32);  bh2[1] = *(const us8*)(bh_src + k0 + 40);
            bl2[0] = *(const us8*)(bl_src + k0 + 32);  bl2[1] = *(const us8*)(bl_src + k0 + 40);
        }
        const int ks = k0 >> 5;
        us8 afh[4], afl[4];
#pragma unroll
        for (int m = 0; m < 4; m++) {
            const size_t ao = abase + (size_t)(m * 32 + ks) * 512;
            afh[m] = *(const us8*)(h1t_hi + ao);
            afl[m] = *(const us8*)(h1t_lo + ao);
        }
#pragma unroll
        for (int n = 0; n < 4; n++) {
            us8 bfh = *(const us8*)(&Bh[wn * 64 + n * 16 + fr][fk]);
            us8 bfl = *(const us8*)(&Bl[wn * 64 + n * 16 + fr][fk]);
#pragma unroll
            for (int m = 0; m < 4; m++) {
                acc[m][n] = mfma16(afh[m], bfh, acc[m][n]);
                acc[m][n] = mfma16(afh[m], bfl, acc[m][n]);
                acc[m][n] = mfma16(afl[m], bfh, acc[m][n]);
            }
        }
    }
    const int fq = lane >> 4;
#pragma unroll
    for (int m = 0; m < 4; m++)
#pragma unroll
        for (int n = 0; n < 4; n++)
#pragma unroll
            for (int i = 0; i < 4; i++) {
                int r = row0 + wm * 64 + m * 16 + fq * 4 + i;
                int c = col0 + wn * 64 + n * 16 + fr;
                float v = acc[m][n][i] + bias[c];
                if (c < VOCAB) C[(size_t)r * VOCAB + c] = v;
            }
}

// ---------------- single-kernel step: full K in one block, no cross-block comm ----------
// grid 64 (1 block per jc), 512 thr = 8 waves, 1 block/CU (256 VGPR budget).
// Wave w sums ks = 4w..4w+3 sequentially in registers (m-loop x4: every weight/A byte
// read ONCE per block, ~589 KB through L1). 8->1 LDS tree reduce gives full-K sums
// in-block; final sums published to LDS; all 512 threads do the GRU pointwise.
// No P buffer, no fences, no second kernel.
template <int T0, int T1>
__global__ __launch_bounds__(512, 1)
void step_kernel(const unsigned short* __restrict__ h0hi, const unsigned short* __restrict__ h0lo,
                 const unsigned short* __restrict__ h1hi, const unsigned short* __restrict__ h1lo,
                 const unsigned short* __restrict__ Wthi, const unsigned short* __restrict__ Wtlo,
                 const float* __restrict__ gx0next,
                 const float* __restrict__ bw0, const float* __restrict__ bu0,
                 const float* __restrict__ bw1, const float* __restrict__ bu1,
                 unsigned short* __restrict__ h0o_hi, unsigned short* __restrict__ h0o_lo,
                 unsigned short* __restrict__ h1o_hi, unsigned short* __restrict__ h1o_lo)
{
    const int tid = threadIdx.x, lane = tid & 63, wave = tid >> 6;
    const int jc = blockIdx.x;

    f4v acc[9][4] = {};
    us8 ah[4], al[4];

#pragma unroll
    for (int ksl = 0; ksl < 4; ksl++) {
        const int ks = wave * 4 + ksl;
        const size_t abase = ((size_t)ks * 64 + lane) * 8;
        // phase A: t2 in [T0, min(6,T1)) uses h0 fragments
        if (T0 < 6) {
#pragma unroll
            for (int m = 0; m < 4; m++) {
                ah[m] = *(const us8*)(h0hi + abase + (size_t)m * 16384);
                al[m] = *(const us8*)(h0lo + abase + (size_t)m * 16384);
            }
#pragma unroll
            for (int t2 = T0; t2 < ((T1 < 6) ? T1 : 6); ++t2) {
                const int mat = t2 / 3, g = t2 % 3;
                const size_t base = (((size_t)(mat * 192 + g * 64 + jc) * 32 + ks) * 64 + lane) * 8;
                us8 bh = *(const us8*)(Wthi + base);
                us8 bl = *(const us8*)(Wtlo + base);
#pragma unroll
                for (int m = 0; m < 4; ++m) {
                    acc[t2][m] = mfma16(ah[m], bh, acc[t2][m]);
                    acc[t2][m] = mfma16(ah[m], bl, acc[t2][m]);
                    acc[t2][m] = mfma16(al[m], bh, acc[t2][m]);
                }
            }
        }
        // phase B: t2 in [6, T1) uses h1 fragments (reuse the same registers)
        if (T1 > 6) {
#pragma unroll
            for (int m = 0; m < 4; m++) {
                ah[m] = *(const us8*)(h1hi + abase + (size_t)m * 16384);
                al[m] = *(const us8*)(h1lo + abase + (size_t)m * 16384);
            }
#pragma unroll
            for (int t2 = 6; t2 < T1; ++t2) {
                const int g = t2 % 3;
                const size_t base = (((size_t)(2 * 192 + g * 64 + jc) * 32 + ks) * 64 + lane) * 8;
                us8 bh = *(const us8*)(Wthi + base);
                us8 bl = *(const us8*)(Wtlo + base);
#pragma unroll
                for (int m = 0; m < 4; ++m) {
                    acc[t2][m] = mfma16(ah[m], bh, acc[t2][m]);
                    acc[t2][m] = mfma16(ah[m], bl, acc[t2][m]);
                    acc[t2][m] = mfma16(al[m], bh, acc[t2][m]);
                }
            }
        }
    }

    // 8 -> 1 tree reduce over waves, chunked 3 t2 at a time (48 KB LDS)
    __shared__ f4v red[4][3][4][64];
    const int c0lo = T0 / 3, c0hi = (T1 + 2) / 3;
#pragma unroll
    for (int stride = 4; stride >= 1; stride >>= 1) {
#pragma unroll
        for (int c = c0lo; c < c0hi; ++c) {
            if (wave >= stride && wave < 2 * stride) {
#pragma unroll
                for (int u = 0; u < 3; ++u) {
                    const int t2 = c * 3 + u;
                    if (t2 >= T0 && t2 < T1) {
#pragma unroll
                        for (int m = 0; m < 4; ++m)
                            red[wave - stride][u][m][lane] = acc[t2][m];
                    }
                }
            }
            __syncthreads();
            if (wave < stride) {
#pragma unroll
                for (int u = 0; u < 3; ++u) {
                    const int t2 = c * 3 + u;
                    if (t2 >= T0 && t2 < T1) {
#pragma unroll
                        for (int m = 0; m < 4; ++m)
                            acc[t2][m] += red[wave][u][m][lane];
                    }
                }
            }
            __syncthreads();
        }
    }

    // publish full-K sums to LDS (reuse red storage): redF[(t2*4+m)*64+lane] = acc[t2][m]
    f4v* redF = &red[0][0][0][0];
    if (wave == 0) {
#pragma unroll
        for (int t2 = T0; t2 < T1; ++t2)
#pragma unroll
            for (int m = 0; m < 4; ++m)
                redF[(t2 * 4 + m) * 64 + lane] = acc[t2][m];
    }
    __syncthreads();
    const float* redS = (const float*)redF;

    // pointwise: 1024 (b,j) pairs, 2 per thread.
    // G[t2](b,j) lives at redF[(t2*4 + (b>>4))*64 + ((b>>2)&3)*16 + (j&15)][b&3]
#pragma unroll
    for (int k = 0; k < 2; ++k) {
        const int idx = k * 512 + tid;
        const int b = idx >> 4, jl = idx & 15;
        const int j = jc * 16 + jl;
        const int lreg = ((b >> 2) & 3) * 16 + jl, e = b & 3;
        float G[9];
#pragma unroll
        for (int t2 = T0; t2 < T1; ++t2)
            G[t2] = redS[(((t2 * 4 + (b >> 4)) * 64 + lreg) << 2) + e];
        const size_t po = htile_off(b, j);
        if (T0 == 0) {
            float sr  = gx0next[(size_t)b * G3 + j]            + bw0[j]           + G[0] + bu0[j];
            float sz  = gx0next[(size_t)b * G3 + HID + j]      + bw0[HID + j]     + G[1] + bu0[HID + j];
            float gxn = gx0next[(size_t)b * G3 + 2 * HID + j]  + bw0[2 * HID + j];
            float ghn = G[2] + bu0[2 * HID + j];
            float r = sigmoidf_(sr);
            float z = sigmoidf_(sz);
            float ht = tanhf(gxn + r * ghn);
            float hp = bf2f(h0hi[po]) + bf2f(h0lo[po]);
            float hn = (1.f - z) * hp + z * ht;
            unsigned short hh, hl2; split2(hn, hh, hl2);
            h0o_hi[po] = hh; h0o_lo[po] = hl2;
        }
        if (T1 > 3) {
            float sr  = G[3] + bw1[j]           + G[6] + bu1[j];
            float sz  = G[4] + bw1[HID + j]     + G[7] + bu1[HID + j];
            float gxn = G[5] + bw1[2 * HID + j];
            float ghn = G[8] + bu1[2 * HID + j];
            float r = sigmoidf_(sr);
            float z = sigmoidf_(sz);
            float ht = tanhf(gxn + r * ghn);
            float hp = bf2f(h1hi[po]) + bf2f(h1lo[po]);
            float hn = (1.f - z) * hp + z * ht;
            unsigned short hh, hl2; split2(hn, hh, hl2);
            h1o_hi[po] = hh; h1o_lo[po] = hl2;
        }
    }
}

// ---------------- final hidden output ----------
__global__ void hidden_out_kernel(const unsigned short* __restrict__ h0hi, const unsigned short* __restrict__ h0lo,
                                  const unsigned short* __restrict__ h1hi, const unsigned short* __restrict__ h1lo,
                                  float* __restrict__ out)
{
    int i = blockIdx.x * 256 + threadIdx.x;
    if (i < BATCHN * HID) {
        int b = i >> 10, j = i & 1023;
        size_t o = htile_off(b, j);
        out[i] = bf2f(h0hi[o]) + bf2f(h0lo[o]);
        out[BATCHN * HID + i] = bf2f(h1hi[o]) + bf2f(h1lo[o]);
    }
}

extern "C" void kernel_launch(void* const* d_in, const int* in_sizes, int n_in,
                              void* d_out, int out_size, void* d_ws, size_t ws_size,
                              hipStream_t stream)
{
    (void)in_sizes; (void)n_in; (void)out_size;
    const int*   tok    = (const int*)  d_in[0];
    const float* hidden = (const float*)d_in[1];
    const float* emb    = (const float*)d_in[2];
    const float* W0     = (const float*)d_in[3];
    const float* U0     = (const float*)d_in[4];
    const float* bw0    = (const float*)d_in[5];
    const float* bu0    = (const float*)d_in[6];
    const float* W1     = (const float*)d_in[7];
    const float* U1     = (const float*)d_in[8];
    const float* bw1    = (const float*)d_in[9];
    const float* bu1    = (const float*)d_in[10];
    const float* fcW    = (const float*)d_in[11];
    const float* fcb    = (const float*)d_in[12];
    float* out = (float*)d_out;

    char* wsp = (char*)d_ws;
    size_t used = 0;
    auto alloc = [&](size_t bytes) -> char* {
        char* p = wsp + used;
        used += (bytes + 255) & ~(size_t)255;
        return p;
    };
    unsigned short* Wt_hi = (unsigned short*)alloc((size_t)4 * G3 * HID * 2);   // 25.2 MB
    unsigned short* Wt_lo = (unsigned short*)alloc((size_t)4 * G3 * HID * 2);   // 25.2 MB
    float*          GX0   = (float*)alloc((size_t)AROWS * G3 * 4);              // 50.3 MB
    unsigned short* H0Thi = (unsigned short*)alloc((size_t)SEQL * HSLOT * 2);   // 8.4 MB
    unsigned short* H0Tlo = (unsigned short*)alloc((size_t)SEQL * HSLOT * 2);
    unsigned short* H1Thi = (unsigned short*)alloc((size_t)SEQL * HSLOT * 2);
    unsigned short* H1Tlo = (unsigned short*)alloc((size_t)SEQL * HSLOT * 2);
    unsigned short* h0ith = (unsigned short*)alloc((size_t)HSLOT * 2);
    unsigned short* h0itl = (unsigned short*)alloc((size_t)HSLOT * 2);
    unsigned short* h1ith = (unsigned short*)alloc((size_t)HSLOT * 2);
    unsigned short* h1itl = (unsigned short*)alloc((size_t)HSLOT * 2);
    if (used > ws_size) return;  // ~135 MB needed

    unsigned short* fcWhi = Wt_hi;   // aliases dead Wt space (used only after last step)
    unsigned short* fcWlo = Wt_lo;
    float*          fcbp  = (float*)((char*)Wt_hi + (size_t)NPAD * HID * 2);

    tile_weights_kernel<<<dim3(48, 32, 4), 256, 0, stream>>>(U0, W1, U1, W0, Wt_hi, Wt_lo);
    small_prep_kernel<<<256, 256, 0, stream>>>(hidden, h0ith, h0itl, h1ith, h1itl);
    gx0_gemm_kernel<<<768, 256, 0, stream>>>(tok, emb, Wt_hi, Wt_lo, GX0);

    // prologue: h0_0 = GRU0(gx0[0], h_init0)
    step_kernel<0, 3><<<64, 512, 0, stream>>>(
        h0ith, h0itl, h1ith, h1itl, Wt_hi, Wt_lo,
        GX0, bw0, bu0, bw1, bu1,
        H0Thi, H0Tlo,                                       // h0_0 -> slot 0
        H1Thi + (size_t)63 * HSLOT, H1Tlo + (size_t)63 * HSLOT);  // unused (compiled out)

    for (int t = 0; t < 63; t++) {
        const unsigned short* h0h = H0Thi + (size_t)t * HSLOT;
        const unsigned short* h0l = H0Tlo + (size_t)t * HSLOT;
        const unsigned short* a1h = (t == 0) ? h1ith : H1Thi + (size_t)(t - 1) * HSLOT;
        const unsigned short* a1l = (t == 0) ? h1itl : H1Tlo + (size_t)(t - 1) * HSLOT;
        step_kernel<0, 9><<<64, 512, 0, stream>>>(
            h0h, h0l, a1h, a1l, Wt_hi, Wt_lo,
            GX0 + (size_t)(t + 1) * BATCHN * G3, bw0, bu0, bw1, bu1,
            H0Thi + (size_t)(t + 1) * HSLOT, H0Tlo + (size_t)(t + 1) * HSLOT,  // h0_{t+1}
            H1Thi + (size_t)t * HSLOT, H1Tlo + (size_t)t * HSLOT);             // h1_t
    }
    // t = 63: layer-1 only
    step_kernel<3, 9><<<64, 512, 0, stream>>>(
        H0Thi + (size_t)63 * HSLOT, H0Tlo + (size_t)63 * HSLOT,
        H1Thi + (size_t)62 * HSLOT, H1Tlo + (size_t)62 * HSLOT,
        Wt_hi, Wt_lo,
        GX0, bw0, bu0, bw1, bu1,
        h0ith, h0itl,                                              // unused (compiled out)
        H1Thi + (size_t)63 * HSLOT, H1Tlo + (size_t)63 * HSLOT);   // h1_63

    hidden_out_kernel<<<256, 256, 0, stream>>>(
        H0Thi + (size_t)63 * HSLOT, H0Tlo + (size_t)63 * HSLOT,
        H1Thi + (size_t)63 * HSLOT, H1Tlo + (size_t)63 * HSLOT,
        out + (size_t)AROWS * VOCAB);

    fc_pad_split_kernel<<<NPAD, 256, 0, stream>>>(fcW, fcWhi, fcWlo);
    fcb_pad_kernel<<<(NPAD + 255) / 256, 256, 0, stream>>>(fcb, fcbp);
    logits_gemm_kernel<<<2560, 256, 0, stream>>>(
        H1Thi, H1Tlo, fcWhi, fcWlo, fcbp, out);
}

// Round 10
// 1554.713 us; speedup vs baseline: 3.7202x; 1.5074x over previous
//
#include <hip/hip_runtime.h>
#include <math.h>

#define SEQL 64
#define BATCHN 64
#define HID 1024
#define EMBD 1024
#define VOCAB 10000
#define G3 3072
#define NPAD 10240   // 80*128 = 640 col-chunks of 16
#define AROWS 4096   // SEQL*BATCHN
#define HSLOT 65536  // BATCHN*HID elements per t-slot

typedef float f4v __attribute__((ext_vector_type(4)));
typedef unsigned short us4 __attribute__((ext_vector_type(4)));
typedef unsigned short us8 __attribute__((ext_vector_type(8)));
typedef __bf16 bf8v __attribute__((ext_vector_type(8)));

__device__ __forceinline__ unsigned short f2bf(float f) {
    unsigned u = __float_as_uint(f);
    u += 0x7fffu + ((u >> 16) & 1u);
    return (unsigned short)(u >> 16);
}
__device__ __forceinline__ float bf2f(unsigned short h) {
    return __uint_as_float(((unsigned)h) << 16);
}
__device__ __forceinline__ void split2(float f, unsigned short &hi, unsigned short &lo) {
    hi = f2bf(f);
    lo = f2bf(f - bf2f(hi));
}
__device__ __forceinline__ f4v mfma16(us8 a, us8 b, f4v c) {
    return __builtin_amdgcn_mfma_f32_16x16x32_bf16(
        __builtin_bit_cast(bf8v, a), __builtin_bit_cast(bf8v, b), c, 0, 0, 0);
}
__device__ __forceinline__ float sigmoidf_(float x) { return 1.f / (1.f + expf(-x)); }

// tiled layout for h within one t-slot: [(b>>4)*32 + (j>>5)][lane=((j>>3)&3)*16+(b&15)][e=j&7]
__device__ __forceinline__ size_t htile_off(int b, int j) {
    return ((size_t)((((b >> 4) * 32 + (j >> 5)) * 64) + ((j >> 3) & 3) * 16 + (b & 15))) * 8 + (j & 7);
}

// ---------------- prep: tile 4 weight matrices into MFMA B-fragment order ----------
// mats: 0=U0, 1=W1, 2=U1, 3=W0
__global__ __launch_bounds__(256)
void tile_weights_kernel(const float* __restrict__ U0, const float* __restrict__ W1,
                         const float* __restrict__ U1, const float* __restrict__ W0,
                         unsigned short* __restrict__ hi, unsigned short* __restrict__ lo)
{
    __shared__ float tile[32][65];
    const int mat = blockIdx.z;
    const float* src = (mat == 0) ? U0 : (mat == 1) ? W1 : (mat == 2) ? U1 : W0;
    const int n0 = blockIdx.x * 64, k0 = blockIdx.y * 32;
    const int t = threadIdx.x, tx = t & 63, ty = t >> 6;
#pragma unroll
    for (int s = 0; s < 8; s++)
        tile[ty * 8 + s][tx] = src[(size_t)(k0 + ty * 8 + s) * G3 + n0 + tx];
    __syncthreads();
    const int c = t >> 6, lane = t & 63, fr = lane & 15, kg = lane >> 4;
    const int cc = (n0 >> 4) + c;
    const size_t off = (((size_t)(mat * 192 + cc) * 32 + (k0 >> 5)) * 64 + lane) * 8;
    us8 h8, l8;
#pragma unroll
    for (int e = 0; e < 8; e++) {
        unsigned short a, b;
        split2(tile[kg * 8 + e][c * 16 + fr], a, b);
        h8[e] = a; l8[e] = b;
    }
    *(us8*)(hi + off) = h8;
    *(us8*)(lo + off) = l8;
}

// ---------------- prep (late): fcW -> MFMA B-fragments, padded to NPAD rows ----------
// out[((cc*32 + ks)*64 + lane)*8 + e] = split(fcW[cc*16 + (lane&15)][ks*32 + (lane>>4)*8 + e])
__global__ __launch_bounds__(256)
void tile_fc_kernel(const float* __restrict__ fcW,
                    unsigned short* __restrict__ hi, unsigned short* __restrict__ lo)
{
    const int cc = blockIdx.x;
    const int tid = threadIdx.x;
#pragma unroll
    for (int q = 0; q < 8; q++) {
        const int o = tid * 8 + q;         // 0..2047
        const int ks = o >> 6, lane = o & 63;
        const int fr = lane & 15, kg = lane >> 4;
        const int row = cc * 16 + fr;
        const int col = ks * 32 + kg * 8;
        us8 h8, l8;
        if (row < VOCAB) {
            f4v v0 = *(const f4v*)(fcW + (size_t)row * HID + col);
            f4v v1 = *(const f4v*)(fcW + (size_t)row * HID + col + 4);
#pragma unroll
            for (int e = 0; e < 4; e++) {
                unsigned short a, b;
                split2(v0[e], a, b); h8[e] = a; l8[e] = b;
                split2(v1[e], a, b); h8[4 + e] = a; l8[4 + e] = b;
            }
        } else {
            h8 = (us8){0,0,0,0,0,0,0,0};
            l8 = (us8){0,0,0,0,0,0,0,0};
        }
        const size_t off = (((size_t)cc * 32 + ks) * 64 + lane) * 8;
        *(us8*)(hi + off) = h8;
        *(us8*)(lo + off) = l8;
    }
}

__global__ void fcb_pad_kernel(const float* __restrict__ fcb, float* __restrict__ fcb_pad)
{
    int idx = blockIdx.x * 256 + threadIdx.x;
    if (idx < NPAD) fcb_pad[idx] = (idx < VOCAB) ? fcb[idx] : 0.f;
}

// ---------------- prep: initial hidden -> tiled hi/lo ----------
__global__ void small_prep_kernel(const float* __restrict__ hidden,
                                  unsigned short* __restrict__ h0th, unsigned short* __restrict__ h0tl,
                                  unsigned short* __restrict__ h1th, unsigned short* __restrict__ h1tl)
{
    int idx = blockIdx.x * 256 + threadIdx.x;
    if (idx < BATCHN * HID) {
        int b = idx >> 10, j = idx & 1023;
        size_t o = htile_off(b, j);
        unsigned short a1, b1;
        split2(hidden[idx], a1, b1);                 h0th[o] = a1; h0tl[o] = b1;
        split2(hidden[BATCHN * HID + idx], a1, b1);  h1th[o] = a1; h1tl[o] = b1;
    }
}

// ---------------- GX0 = gather(emb,tok) @ W0 ----------
__global__ __launch_bounds__(256)
void gx0_gemm_kernel(const int* __restrict__ tok, const float* __restrict__ emb,
                     const unsigned short* __restrict__ Wthi, const unsigned short* __restrict__ Wtlo,
                     float* __restrict__ C)
{
    __shared__ unsigned short Ah[128][40], Al[128][40];
    const int bswz = blockIdx.x;
    const int xcd = bswz & 7, s = bswz >> 3;
    const int col0 = (xcd + 8 * (s >> 5)) * 128;   // 24 col-tiles
    const int row0 = (s & 31) * 128;               // 32 row-tiles
    const int tid = threadIdx.x;
    const int lane = tid & 63, wave = tid >> 6;
    const int wm = wave >> 1, wn = wave & 1;
    const int srow = tid >> 1;
    const int shalf = (tid & 1) * 16;

    const float* asrc = emb + (size_t)tok[row0 + srow] * EMBD + shalf;
    const int fr = lane & 15, fk = (lane >> 4) * 8;
    const int cc0 = (col0 >> 4) + wn * 4;

    f4v a[4];
#pragma unroll
    for (int q = 0; q < 4; q++) a[q] = *(const f4v*)(asrc + q * 4);

    f4v acc[4][4] = {};
    for (int k0 = 0; k0 < EMBD; k0 += 32) {
        __syncthreads();
        us8 ahv[2], alv[2];
#pragma unroll
        for (int q = 0; q < 4; q++)
#pragma unroll
            for (int j = 0; j < 4; j++) {
                unsigned short h, l;
                split2(a[q][j], h, l);
                ahv[q >> 1][(q & 1) * 4 + j] = h;
                alv[q >> 1][(q & 1) * 4 + j] = l;
            }
        *(us8*)(&Ah[srow][shalf]) = ahv[0];     *(us8*)(&Ah[srow][shalf + 8]) = ahv[1];
        *(us8*)(&Al[srow][shalf]) = alv[0];     *(us8*)(&Al[srow][shalf + 8]) = alv[1];
        __syncthreads();
        if (k0 + 32 < EMBD) {
#pragma unroll
            for (int q = 0; q < 4; q++) a[q] = *(const f4v*)(asrc + k0 + 32 + q * 4);
        }
        const int ks = k0 >> 5;
        us8 bfh[4], bfl[4];
#pragma unroll
        for (int n = 0; n < 4; n++) {
            const size_t bo = (((size_t)(3 * 192 + cc0 + n) * 32 + ks) * 64 + lane) * 8;
            bfh[n] = *(const us8*)(Wthi + bo);
            bfl[n] = *(const us8*)(Wtlo + bo);
        }
        us8 afh[4], afl[4];
#pragma unroll
        for (int m = 0; m < 4; m++) {
            afh[m] = *(const us8*)(&Ah[wm * 64 + m * 16 + fr][fk]);
            afl[m] = *(const us8*)(&Al[wm * 64 + m * 16 + fr][fk]);
        }
#pragma unroll
        for (int n = 0; n < 4; n++)
#pragma unroll
            for (int m = 0; m < 4; m++) {
                acc[m][n] = mfma16(afh[m], bfh[n], acc[m][n]);
                acc[m][n] = mfma16(afh[m], bfl[n], acc[m][n]);
                acc[m][n] = mfma16(afl[m], bfh[n], acc[m][n]);
            }
    }
    const int fq = lane >> 4;
#pragma unroll
    for (int m = 0; m < 4; m++)
#pragma unroll
        for (int n = 0; n < 4; n++)
#pragma unroll
            for (int i = 0; i < 4; i++) {
                int r = row0 + wm * 64 + m * 16 + fq * 4 + i;
                int c = col0 + wn * 64 + n * 16 + fr;
                C[(size_t)r * G3 + c] = acc[m][n][i];
            }
}

// ---------------- logits = H1 @ fcW^T + fcb ; A and B both direct fragment loads ----------
// No LDS, no barriers: A from tiled per-t h1, B from pre-tiled fcW fragments.
__global__ __launch_bounds__(256)
void logits_gemm_kernel(const unsigned short* __restrict__ h1t_hi, const unsigned short* __restrict__ h1t_lo,
                        const unsigned short* __restrict__ Bhi, const unsigned short* __restrict__ Blo,
                        const float* __restrict__ bias, float* __restrict__ C)
{
    const int bswz = blockIdx.x;
    const int xcd = bswz & 7, s = bswz >> 3;
    const int col0 = (xcd + 8 * (s >> 5)) * 128;   // 80 col-tiles
    const int row0 = (s & 31) * 128;               // 32 row-tiles
    const int t0 = row0 >> 6;
    const int tid = threadIdx.x;
    const int lane = tid & 63, wave = tid >> 6;
    const int wm = wave >> 1, wn = wave & 1;
    const int fr = lane & 15;
    const int cc0 = (col0 >> 4) + wn * 4;

    f4v acc[4][4] = {};
    const size_t abase = ((size_t)(t0 + wm) * 128) * 512 + (size_t)lane * 8;

    for (int ks = 0; ks < 32; ks++) {
        us8 afh[4], afl[4], bfh[4], bfl[4];
#pragma unroll
        for (int m = 0; m < 4; m++) {
            const size_t ao = abase + (size_t)(m * 32 + ks) * 512;
            afh[m] = *(const us8*)(h1t_hi + ao);
            afl[m] = *(const us8*)(h1t_lo + ao);
        }
#pragma unroll
        for (int n = 0; n < 4; n++) {
            const size_t bo = (((size_t)(cc0 + n) * 32 + ks) * 64 + lane) * 8;
            bfh[n] = *(const us8*)(Bhi + bo);
            bfl[n] = *(const us8*)(Blo + bo);
        }
#pragma unroll
        for (int n = 0; n < 4; n++)
#pragma unroll
            for (int m = 0; m < 4; m++) {
                acc[m][n] = mfma16(afh[m], bfh[n], acc[m][n]);
                acc[m][n] = mfma16(afh[m], bfl[n], acc[m][n]);
                acc[m][n] = mfma16(afl[m], bfh[n], acc[m][n]);
            }
    }
    const int fq = lane >> 4;
#pragma unroll
    for (int m = 0; m < 4; m++)
#pragma unroll
        for (int n = 0; n < 4; n++)
#pragma unroll
            for (int i = 0; i < 4; i++) {
                int r = row0 + wm * 64 + m * 16 + fq * 4 + i;
                int c = col0 + wn * 64 + n * 16 + fr;
                float v = acc[m][n][i] + bias[c];
                if (c < VOCAB) C[(size_t)r * VOCAB + c] = v;
            }
}

// ---------------- step GEMM: grid 512 = 64 jc x 8 kh, 256 thr (4 waves, 2 blocks/CU) ----------
// Wave w owns ks = kh*4 + w, m-loop x4: every weight/A byte read once per block (~104 KB).
// Two-phase A-register reuse. 4->1 direct LDS reduce (2-t2 chunks, 10 syncs total);
// kh-partial written to P[kh][t2][b][j].
template <int T0, int T1>
__global__ __launch_bounds__(256)
void step_gemm_kernel(const unsigned short* __restrict__ h0hi, const unsigned short* __restrict__ h0lo,
                      const unsigned short* __restrict__ h1hi, const unsigned short* __restrict__ h1lo,
                      const unsigned short* __restrict__ Wthi, const unsigned short* __restrict__ Wtlo,
                      float* __restrict__ P)
{
    const int tid = threadIdx.x, lane = tid & 63, wave = tid >> 6;
    const int jc = blockIdx.x >> 3, kh = blockIdx.x & 7;
    const int ks = kh * 4 + wave;
    const size_t abase = ((size_t)ks * 64 + lane) * 8;

    f4v acc[9][4] = {};
    us8 ah[4], al[4];

    // phase A: t2 in [T0, min(6,T1)) uses h0 fragments
    if (T0 < 6) {
#pragma unroll
        for (int m = 0; m < 4; m++) {
            ah[m] = *(const us8*)(h0hi + abase + (size_t)m * 16384);
            al[m] = *(const us8*)(h0lo + abase + (size_t)m * 16384);
        }
#pragma unroll
        for (int t2 = T0; t2 < ((T1 < 6) ? T1 : 6); ++t2) {
            const int mat = t2 / 3, g = t2 % 3;
            const size_t base = (((size_t)(mat * 192 + g * 64 + jc) * 32 + ks) * 64 + lane) * 8;
            us8 bh = *(const us8*)(Wthi + base);
            us8 bl = *(const us8*)(Wtlo + base);
#pragma unroll
            for (int m = 0; m < 4; ++m) {
                acc[t2][m] = mfma16(ah[m], bh, acc[t2][m]);
                acc[t2][m] = mfma16(ah[m], bl, acc[t2][m]);
                acc[t2][m] = mfma16(al[m], bh, acc[t2][m]);
            }
        }
    }
    // phase B: t2 in [6, T1) uses h1 fragments (reuse the same registers)
    if (T1 > 6) {
#pragma unroll
        for (int m = 0; m < 4; m++) {
            ah[m] = *(const us8*)(h1hi + abase + (size_t)m * 16384);
            al[m] = *(const us8*)(h1lo + abase + (size_t)m * 16384);
        }
#pragma unroll
        for (int t2 = 6; t2 < T1; ++t2) {
            const int g = t2 % 3;
            const size_t base = (((size_t)(2 * 192 + g * 64 + jc) * 32 + ks) * 64 + lane) * 8;
            us8 bh = *(const us8*)(Wthi + base);
            us8 bl = *(const us8*)(Wtlo + base);
#pragma unroll
            for (int m = 0; m < 4; ++m) {
                acc[t2][m] = mfma16(ah[m], bh, acc[t2][m]);
                acc[t2][m] = mfma16(ah[m], bl, acc[t2][m]);
                acc[t2][m] = mfma16(al[m], bh, acc[t2][m]);
            }
        }
    }

    // 4 -> 1 reduce over waves, chunks of 2 t2 (32 KB LDS, 2 syncs/chunk)
    __shared__ f4v red[4][2][4][64];
    const int rrow = (lane >> 4) * 4, rcol = lane & 15;
#pragma unroll
    for (int c = 0; c < 5; ++c) {
        const int ta = 2 * c, tb = 2 * c + 1;
        if (tb >= T0 && ta < T1) {
#pragma unroll
            for (int u = 0; u < 2; ++u) {
                const int t2 = 2 * c + u;
                if (t2 >= T0 && t2 < T1) {
#pragma unroll
                    for (int m = 0; m < 4; ++m)
                        red[wave][u][m][lane] = acc[t2][m];
                }
            }
            __syncthreads();
#pragma unroll
            for (int s2 = 0; s2 < 2; ++s2) {
                const int combo = wave * 2 + s2;       // 0..7
                const int u = combo >> 2, m = combo & 3;
                const int t2 = 2 * c + u;
                if (t2 >= T0 && t2 < T1) {
                    f4v v = (red[0][u][m][lane] + red[1][u][m][lane])
                          + (red[2][u][m][lane] + red[3][u][m][lane]);
#pragma unroll
                    for (int i = 0; i < 4; ++i)
                        P[(((size_t)kh * 9 + t2) * 64 + (m * 16 + rrow + i)) * 1024 + jc * 16 + rcol]
                            = v[i];
                }
            }
            __syncthreads();
        }
    }
}

// ---------------- step reduce: sum 8 kh-partials + fused GRU pointwise ----------
// grid 256 x 256 thr: one thread per (b, j).
template <int T0, int T1>
__global__ __launch_bounds__(256)
void step_reduce_kernel(const float* __restrict__ P, const float* __restrict__ gx0next,
                        const float* __restrict__ bw0, const float* __restrict__ bu0,
                        const float* __restrict__ bw1, const float* __restrict__ bu1,
                        const unsigned short* __restrict__ h0hi, const unsigned short* __restrict__ h0lo,
                        const unsigned short* __restrict__ h1hi, const unsigned short* __restrict__ h1lo,
                        unsigned short* __restrict__ h0o_hi, unsigned short* __restrict__ h0o_lo,
                        unsigned short* __restrict__ h1o_hi, unsigned short* __restrict__ h1o_lo)
{
    const int idx = blockIdx.x * 256 + threadIdx.x;
    const int b = idx >> 10, j = idx & 1023;
    float G[9];
#pragma unroll
    for (int t2 = T0; t2 < T1; t2++) {
        const float* p = P + ((size_t)t2 * 64 + b) * 1024 + j;
        float s0 = 0.f, s1 = 0.f;
#pragma unroll
        for (int kh = 0; kh < 4; kh++) {
            s0 += p[(size_t)(kh * 9) * 64 * 1024];
            s1 += p[(size_t)((kh + 4) * 9) * 64 * 1024];
        }
        G[t2] = s0 + s1;
    }
    const size_t po = htile_off(b, j);
    if (T0 == 0) {
        float sr  = gx0next[(size_t)b * G3 + j]            + bw0[j]           + G[0] + bu0[j];
        float sz  = gx0next[(size_t)b * G3 + HID + j]      + bw0[HID + j]     + G[1] + bu0[HID + j];
        float gxn = gx0next[(size_t)b * G3 + 2 * HID + j]  + bw0[2 * HID + j];
        float ghn = G[2] + bu0[2 * HID + j];
        float r = sigmoidf_(sr);
        float z = sigmoidf_(sz);
        float ht = tanhf(gxn + r * ghn);
        float hp = bf2f(h0hi[po]) + bf2f(h0lo[po]);
        float hn = (1.f - z) * hp + z * ht;
        unsigned short hh, hl2; split2(hn, hh, hl2);
        h0o_hi[po] = hh; h0o_lo[po] = hl2;
    }
    if (T1 > 3) {
        float sr  = G[3] + bw1[j]           + G[6] + bu1[j];
        float sz  = G[4] + bw1[HID + j]     + G[7] + bu1[HID + j];
        float gxn = G[5] + bw1[2 * HID + j];
        float ghn = G[8] + bu1[2 * HID + j];
        float r = sigmoidf_(sr);
        float z = sigmoidf_(sz);
        float ht = tanhf(gxn + r * ghn);
        float hp = bf2f(h1hi[po]) + bf2f(h1lo[po]);
        float hn = (1.f - z) * hp + z * ht;
        unsigned short hh, hl2; split2(hn, hh, hl2);
        h1o_hi[po] = hh; h1o_lo[po] = hl2;
    }
}

// ---------------- final hidden output ----------
__global__ void hidden_out_kernel(const unsigned short* __restrict__ h0hi, const unsigned short* __restrict__ h0lo,
                                  const unsigned short* __restrict__ h1hi, const unsigned short* __restrict__ h1lo,
                                  float* __restrict__ out)
{
    int i = blockIdx.x * 256 + threadIdx.x;
    if (i < BATCHN * HID) {
        int b = i >> 10, j = i & 1023;
        size_t o = htile_off(b, j);
        out[i] = bf2f(h0hi[o]) + bf2f(h0lo[o]);
        out[BATCHN * HID + i] = bf2f(h1hi[o]) + bf2f(h1lo[o]);
    }
}

extern "C" void kernel_launch(void* const* d_in, const int* in_sizes, int n_in,
                              void* d_out, int out_size, void* d_ws, size_t ws_size,
                              hipStream_t stream)
{
    (void)in_sizes; (void)n_in; (void)out_size;
    const int*   tok    = (const int*)  d_in[0];
    const float* hidden = (const float*)d_in[1];
    const float* emb    = (const float*)d_in[2];
    const float* W0     = (const float*)d_in[3];
    const float* U0     = (const float*)d_in[4];
    const float* bw0    = (const float*)d_in[5];
    const float* bu0    = (const float*)d_in[6];
    const float* W1     = (const float*)d_in[7];
    const float* U1     = (const float*)d_in[8];
    const float* bw1    = (const float*)d_in[9];
    const float* bu1    = (const float*)d_in[10];
    const float* fcW    = (const float*)d_in[11];
    const float* fcb    = (const float*)d_in[12];
    float* out = (float*)d_out;

    char* wsp = (char*)d_ws;
    size_t used = 0;
    auto alloc = [&](size_t bytes) -> char* {
        char* p = wsp + used;
        used += (bytes + 255) & ~(size_t)255;
        return p;
    };
    unsigned short* Wt_hi = (unsigned short*)alloc((size_t)4 * G3 * HID * 2);   // 25.2 MB
    unsigned short* Wt_lo = (unsigned short*)alloc((size_t)4 * G3 * HID * 2);   // 25.2 MB
    float*          GX0   = (float*)alloc((size_t)AROWS * G3 * 4);              // 50.3 MB
    unsigned short* H0Thi = (unsigned short*)alloc((size_t)SEQL * HSLOT * 2);   // 8.4 MB
    unsigned short* H0Tlo = (unsigned short*)alloc((size_t)SEQL * HSLOT * 2);
    unsigned short* H1Thi = (unsigned short*)alloc((size_t)SEQL * HSLOT * 2);
    unsigned short* H1Tlo = (unsigned short*)alloc((size_t)SEQL * HSLOT * 2);
    float*          P     = (float*)alloc((size_t)8 * 9 * BATCHN * HID * 4);    // 18.9 MB (single)
    unsigned short* h0ith = (unsigned short*)alloc((size_t)HSLOT * 2);
    unsigned short* h0itl = (unsigned short*)alloc((size_t)HSLOT * 2);
    unsigned short* h1ith = (unsigned short*)alloc((size_t)HSLOT * 2);
    unsigned short* h1itl = (unsigned short*)alloc((size_t)HSLOT * 2);
    if (used > ws_size) return;  // ~154 MB needed

    unsigned short* fcWhi = Wt_hi;   // fc fragments alias dead Wt space (20.97 MB < 25.17 MB)
    unsigned short* fcWlo = Wt_lo;
    float*          fcbp  = (float*)((char*)Wt_hi + (size_t)NPAD * HID * 2);

    tile_weights_kernel<<<dim3(48, 32, 4), 256, 0, stream>>>(U0, W1, U1, W0, Wt_hi, Wt_lo);
    small_prep_kernel<<<256, 256, 0, stream>>>(hidden, h0ith, h0itl, h1ith, h1itl);
    gx0_gemm_kernel<<<768, 256, 0, stream>>>(tok, emb, Wt_hi, Wt_lo, GX0);

    // prologue: h0_0 = GRU0(gx0[0], h_init0)
    step_gemm_kernel<0, 3><<<512, 256, 0, stream>>>(
        h0ith, h0itl, h1ith, h1itl, Wt_hi, Wt_lo, P);
    step_reduce_kernel<0, 3><<<256, 256, 0, stream>>>(
        P, GX0, bw0, bu0, bw1, bu1,
        h0ith, h0itl, h1ith, h1itl,
        H0Thi, H0Tlo,                                       // h0_0 -> slot 0
        H1Thi + (size_t)63 * HSLOT, H1Tlo + (size_t)63 * HSLOT);  // unused (compiled out)

    for (int t = 0; t < 63; t++) {
        const unsigned short* h0h = H0Thi + (size_t)t * HSLOT;
        const unsigned short* h0l = H0Tlo + (size_t)t * HSLOT;
        const unsigned short* a1h = (t == 0) ? h1ith : H1Thi + (size_t)(t - 1) * HSLOT;
        const unsigned short* a1l = (t == 0) ? h1itl : H1Tlo + (size_t)(t - 1) * HSLOT;
        step_gemm_kernel<0, 9><<<512, 256, 0, stream>>>(
            h0h, h0l, a1h, a1l, Wt_hi, Wt_lo, P);
        step_reduce_kernel<0, 9><<<256, 256, 0, stream>>>(
            P, GX0 + (size_t)(t + 1) * BATCHN * G3, bw0, bu0, bw1, bu1,
            h0h, h0l, a1h, a1l,
            H0Thi + (size_t)(t + 1) * HSLOT, H0Tlo + (size_t)(t + 1) * HSLOT,  // h0_{t+1}
            H1Thi + (size_t)t * HSLOT, H1Tlo + (size_t)t * HSLOT);             // h1_t
    }
    // t = 63: layer-1 only
    step_gemm_kernel<3, 9><<<512, 256, 0, stream>>>(
        H0Thi + (size_t)63 * HSLOT, H0Tlo + (size_t)63 * HSLOT,
        H1Thi + (size_t)62 * HSLOT, H1Tlo + (size_t)62 * HSLOT,
        Wt_hi, Wt_lo, P);
    step_reduce_kernel<3, 9><<<256, 256, 0, stream>>>(
        P, GX0, bw0, bu0, bw1, bu1,
        H0Thi + (size_t)63 * HSLOT, H0Tlo + (size_t)63 * HSLOT,
        H1Thi + (size_t)62 * HSLOT, H1Tlo + (size_t)62 * HSLOT,
        h0ith, h0itl,                                              // unused (compiled out)
        H1Thi + (size_t)63 * HSLOT, H1Tlo + (size_t)63 * HSLOT);   // h1_63

    hidden_out_kernel<<<256, 256, 0, stream>>>(
        H0Thi + (size_t)63 * HSLOT, H0Tlo + (size_t)63 * HSLOT,
        H1Thi + (size_t)63 * HSLOT, H1Tlo + (size_t)63 * HSLOT,
        out + (size_t)AROWS * VOCAB);

    // fc fragment prep (aliases dead Wt space), then logits
    tile_fc_kernel<<<NPAD / 16, 256, 0, stream>>>(fcW, fcWhi, fcWlo);
    fcb_pad_kernel<<<(NPAD + 255) / 256, 256, 0, stream>>>(fcb, fcbp);
    logits_gemm_kernel<<<2560, 256, 0, stream>>>(
        H1Thi, H1Tlo, fcWhi, fcWlo, fcbp, out);
}